// Round 6
// baseline (361.832 us; speedup 1.0000x reference)
//
#include <hip/hip_runtime.h>
#include <math.h>

#define NB 16
#define NN 16384
#define DD 128
#define KK 10
#define NT 128   // row-tiles (128 rows each) per batch

// ws layout (floats) — every word read is written first; no zero-init, no atomics:
//   hpart2 [NB][NT][DD]   @0        262144   (H2 column-sum partials)
//   hpart1 [NB][NT][DD]   @262144   262144   (H1 column-sum partials, from fold)
//   v1     [NB][KK][DD]   @524288   20480    (scale folded: 1/(N*sqrt(d)))
//   v2     [NB][KK][DD]   @544768   20480
//   spart  [2][NB][NT][40]@565248   163840   (per-tile SE/Yx/Yy/Yz partials)

__device__ __forceinline__ float4 f4add(float4 a, float4 b) {
    return make_float4(a.x + b.x, a.y + b.y, a.z + b.z, a.w + b.w);
}

// Async global->LDS, 16 B per lane. LDS dest is WAVE-UNIFORM base + lane*16
// (m104/m108); global src is per-lane. One instr stages 1 KB per wave.
__device__ __forceinline__ void gload_lds16(const float* g, float* l) {
    __builtin_amdgcn_global_load_lds(
        (const __attribute__((address_space(1))) unsigned int*)g,
        (__attribute__((address_space(3))) unsigned int*)l,
        16, 0, 0);
}

// Split-butterfly reduction: 10 per-lane partials across a 16-lane group.
// Exit: lane l (l<10) holds the 16-lane sum of a[l]. 15 shuffles (vs 40 naive).
// HW-verified rounds 3/5 (absmax 0).
__device__ __forceinline__ float kreduce16(const float a[KK], int l) {
    const bool h8 = (l & 8) != 0;
    const bool h4 = (l & 4) != 0;
    const bool h2 = (l & 2) != 0;
    const bool h1 = (l & 1) != 0;
    float b[8];
#pragma unroll
    for (int i = 0; i < 8; ++i) {
        float hi = (i < 2) ? a[i + 8] : 0.f;
        float give = h8 ? a[i] : hi;
        float keep = h8 ? hi : a[i];
        b[i] = keep + __shfl_xor(give, 8);
    }
    float c[4];
#pragma unroll
    for (int i = 0; i < 4; ++i) {
        float give = h4 ? b[i] : b[i + 4];
        float keep = h4 ? b[i + 4] : b[i];
        c[i] = keep + __shfl_xor(give, 4);
    }
    float d2[2];
#pragma unroll
    for (int i = 0; i < 2; ++i) {
        float give = h2 ? c[i] : c[i + 2];
        float keep = h2 ? c[i + 2] : c[i];
        d2[i] = keep + __shfl_xor(give, 2);
    }
    float give = h1 ? d2[0] : d2[1];
    float keep = h1 ? d2[1] : d2[0];
    return keep + __shfl_xor(give, 1);
}

// ---------------------------------------------------------------------------
// Kernel 1: column-sum partials of H2 only (H1's sum is folded into scores1).
// grid 2048 = 16 batches x 128 chunks of 128 rows. 256 threads.
// 16 NAMED float4 loads before any use -> 16 outstanding per wave. Unchanged
// from round 5 (HW-verified).
__global__ __launch_bounds__(256) void k_sum(const float* __restrict__ H,
                                             float* __restrict__ hpart) {
    int bi = blockIdx.x;
    int b = bi >> 7;
    int chunk = bi & 127;
    const float4* src4 = (const float4*)(H + ((size_t)b * NN + (size_t)chunk * 128) * DD);
    int tid = threadIdx.x;
    float4 x[16];
#pragma unroll
    for (int j = 0; j < 16; ++j) x[j] = src4[j * 256 + tid];
    float4 t0 = f4add(x[0], x[1]),   t1 = f4add(x[2], x[3]);
    float4 t2 = f4add(x[4], x[5]),   t3 = f4add(x[6], x[7]);
    float4 t4 = f4add(x[8], x[9]),   t5 = f4add(x[10], x[11]);
    float4 t6 = f4add(x[12], x[13]), t7 = f4add(x[14], x[15]);
    float4 s = f4add(f4add(f4add(t0, t1), f4add(t2, t3)),
                     f4add(f4add(t4, t5), f4add(t6, t7)));
    // lanes l and l^32 cover the same column group (f4 col = (j*256+tid)%32)
    s.x += __shfl_xor(s.x, 32);
    s.y += __shfl_xor(s.y, 32);
    s.z += __shfl_xor(s.z, 32);
    s.w += __shfl_xor(s.w, 32);
    __shared__ float red[4][32][4];
    int wv = tid >> 6, lane = tid & 63;
    if (lane < 32) {
        red[wv][lane][0] = s.x; red[wv][lane][1] = s.y;
        red[wv][lane][2] = s.z; red[wv][lane][3] = s.w;
    }
    __syncthreads();
    if (tid < 32) {
        float t0s = 0.f, t1s = 0.f, t2s = 0.f, t3s = 0.f;
#pragma unroll
        for (int w = 0; w < 4; ++w) {
            t0s += red[w][tid][0]; t1s += red[w][tid][1];
            t2s += red[w][tid][2]; t3s += red[w][tid][3];
        }
        *(float4*)(hpart + ((size_t)b * NT + chunk) * DD + tid * 4)
            = make_float4(t0s, t1s, t2s, t3s);
    }
}

// ---------------------------------------------------------------------------
// Kernel 2: vdst[b][k][d] = SCALE * sum_e W[k][d][e] * (sum over hpart chunks)[b][e]
// grid 160 = 16 x 10, 128 threads (one per d). Unchanged (HW-verified).
__global__ __launch_bounds__(128) void k_v(const float* __restrict__ W,
                                           const float* __restrict__ hpart,
                                           float* __restrict__ vdst) {
    int bi = blockIdx.x;
    int b = bi / 10;
    int k = bi % 10;
    const float* Wk = W + (size_t)k * DD * DD;
    __shared__ __align__(16) float hs[DD];
    int tid = threadIdx.x;
    const float* hp = hpart + (size_t)b * NT * DD + tid;
    float s = 0.f;
#pragma unroll 8
    for (int c = 0; c < NT; ++c) s += hp[(size_t)c * DD];
    hs[tid] = s;
    __syncthreads();
    const float4* Wrow = (const float4*)(Wk + (size_t)tid * DD);
    const float4* h4p = (const float4*)hs;
    float acc = 0.f;
#pragma unroll 8
    for (int e4 = 0; e4 < 32; ++e4) {
        float4 w4 = Wrow[e4];
        float4 h4 = h4p[e4];
        acc += w4.x * h4.x + w4.y * h4.y + w4.z * h4.z + w4.w * h4.w;
    }
    const float SCALE = (float)(1.0 / (16384.0 * 11.313708498984761));  // 1/(N*sqrt(128))
    vdst[((size_t)b * KK + k) * DD + tid] = acc * SCALE;
}

// ---------------------------------------------------------------------------
// Kernel 3 (NEW): scores via async LDS staging (m97 pattern).
// grid 2048 = 16 batches x 128 tiles of 128 rows. 256 threads.
// Tile = 4 chunks of 32 rows; chunk double-buffered in LDS (2 x 16 KB),
// filled by global_load_lds (4 instrs/wave/chunk = 1 KB each). In-flight
// data sits in the DMA queue, not VGPRs: 16 KB/CU-block x 4 blocks/CU
// outstanding -> streams at full BW even while waves wait at the barrier.
// Issue order per chunk: stage(next) FIRST, then compute(cur), then barrier.
// Compute body identical to round 5 (HW-verified), h read from LDS.
template <bool FOLD>
__global__ __launch_bounds__(256) void k_scores(const float* __restrict__ Hsrc,
                                                const float* __restrict__ Xsrc,
                                                const float* __restrict__ vsrc,
                                                float* __restrict__ spartp,
                                                float* __restrict__ hpartdst) {
    int bi = blockIdx.x;
    int b = bi >> 7;
    int tile = bi & 127;
    int row0 = tile << 7;
    const float* Hb = Hsrc + (size_t)b * NN * DD;
    const float* Xb = Xsrc + (size_t)b * NN * 3;
    const float* vp = vsrc + (size_t)b * KK * DD;

    __shared__ float hb0[32 * DD];         // 16 KB chunk buffer A
    __shared__ float hb1[32 * DD];         // 16 KB chunk buffer B
    __shared__ float4 v_s4[KK * DD / 4];   // 5 KB
    __shared__ float red[4][40];
    __shared__ float4 colred4[4][2][16];   // 2 KB, FOLD only

    int tid = threadIdx.x;
    int wv = tid >> 6, lane = tid & 63;

    // stage v (regular loads) + chunk 0 (async) under one barrier
    for (int i = tid; i < KK * DD / 4; i += 256)
        v_s4[i] = ((const float4*)vp)[i];
    {
        const float* gsrc = Hb + (size_t)(row0 + 8 * wv) * DD + lane * 4;
#pragma unroll
        for (int j = 0; j < 4; ++j)
            gload_lds16(gsrc + j * 256, hb0 + (8 * wv + 2 * j) * DD);
    }

    int g = tid >> 4;       // group 0..15 (4 per wave), 2 rows each
    int l = tid & 15;       // lane within group -> d-slice (cols l*4 and 64+l*4)
    float kmask = (l < KK) ? 1.f : 0.f;

    float pse = 0.f, py0 = 0.f, py1 = 0.f, py2 = 0.f;   // lane owns k = l
    float4 cs0 = make_float4(0.f, 0.f, 0.f, 0.f);       // col sums (FOLD)
    float4 cs1 = make_float4(0.f, 0.f, 0.f, 0.f);

    // chunk 0 X loads (registers)
    int n0 = row0 + g * 2;
    float xa0 = Xb[(size_t)n0 * 3 + 0];
    float xa1 = Xb[(size_t)n0 * 3 + 1];
    float xa2 = Xb[(size_t)n0 * 3 + 2];
    float xb0 = Xb[(size_t)n0 * 3 + 3];
    float xb1 = Xb[(size_t)n0 * 3 + 4];
    float xb2 = Xb[(size_t)n0 * 3 + 5];

    __syncthreads();   // chunk 0 + v_s4 resident

#pragma unroll
    for (int c = 0; c < 4; ++c) {
        const float* bufc = (c & 1) ? hb1 : hb0;
        float* bufn = (c & 1) ? hb0 : hb1;
        float qa0, qa1, qa2, qb0, qb1, qb2;
        if (c < 3) {
            // issue next chunk's staging FIRST (latency hides under compute+wait)
            const float* gsrc = Hb + (size_t)(row0 + (c + 1) * 32 + 8 * wv) * DD + lane * 4;
#pragma unroll
            for (int j = 0; j < 4; ++j)
                gload_lds16(gsrc + j * 256, bufn + (8 * wv + 2 * j) * DD);
            size_t xn = (size_t)(n0 + (c + 1) * 32) * 3;
            qa0 = Xb[xn + 0]; qa1 = Xb[xn + 1]; qa2 = Xb[xn + 2];
            qb0 = Xb[xn + 3]; qb1 = Xb[xn + 4]; qb2 = Xb[xn + 5];
        }
        // compute chunk c from LDS
        const float* hp0 = bufc + (2 * g) * DD + (l << 2);
        float4 h00 = *(const float4*)(hp0);
        float4 h01 = *(const float4*)(hp0 + 64);
        float4 h10 = *(const float4*)(hp0 + DD);
        float4 h11 = *(const float4*)(hp0 + DD + 64);
        if (FOLD) {
            cs0 = f4add(cs0, f4add(h00, h10));
            cs1 = f4add(cs1, f4add(h01, h11));
        }
        float acc0[KK], acc1[KK];
#pragma unroll
        for (int k = 0; k < KK; ++k) {
            float4 v0 = v_s4[k * 32 + l];
            float4 v1 = v_s4[k * 32 + 16 + l];
            acc0[k] = h00.x * v0.x + h00.y * v0.y + h00.z * v0.z + h00.w * v0.w
                    + h01.x * v1.x + h01.y * v1.y + h01.z * v1.z + h01.w * v1.w;
            acc1[k] = h10.x * v0.x + h10.y * v0.y + h10.z * v0.z + h10.w * v0.w
                    + h11.x * v1.x + h11.y * v1.y + h11.z * v1.z + h11.w * v1.w;
        }
        // split-butterfly: lane l ends with the full group sum for k = l
        float s0 = kreduce16(acc0, l);
        float s1 = kreduce16(acc1, l);
        // |s| <~ 0.3 -> exp without max-subtraction is exact softmax semantics.
        float e0 = kmask * __expf(s0);
        float e1 = kmask * __expf(s1);
        pse += e0 + e1;
        py0 += e0 * xa0 + e1 * xb0;
        py1 += e0 * xa1 + e1 * xb1;
        py2 += e0 * xa2 + e1 * xb2;
        if (c < 3) {
            xa0 = qa0; xa1 = qa1; xa2 = qa2;
            xb0 = qb0; xb1 = qb1; xb2 = qb2;
        }
        // drains vmcnt (next chunk resident) and protects buffer reuse
        __syncthreads();
    }
    // reduce across the 4 groups of the wave (xor 16/32 preserves l -> k identity)
    pse += __shfl_xor(pse, 16); pse += __shfl_xor(pse, 32);
    py0 += __shfl_xor(py0, 16); py0 += __shfl_xor(py0, 32);
    py1 += __shfl_xor(py1, 16); py1 += __shfl_xor(py1, 32);
    py2 += __shfl_xor(py2, 16); py2 += __shfl_xor(py2, 32);
    if (FOLD) {
        cs0.x += __shfl_xor(cs0.x, 16); cs0.x += __shfl_xor(cs0.x, 32);
        cs0.y += __shfl_xor(cs0.y, 16); cs0.y += __shfl_xor(cs0.y, 32);
        cs0.z += __shfl_xor(cs0.z, 16); cs0.z += __shfl_xor(cs0.z, 32);
        cs0.w += __shfl_xor(cs0.w, 16); cs0.w += __shfl_xor(cs0.w, 32);
        cs1.x += __shfl_xor(cs1.x, 16); cs1.x += __shfl_xor(cs1.x, 32);
        cs1.y += __shfl_xor(cs1.y, 16); cs1.y += __shfl_xor(cs1.y, 32);
        cs1.z += __shfl_xor(cs1.z, 16); cs1.z += __shfl_xor(cs1.z, 32);
        cs1.w += __shfl_xor(cs1.w, 16); cs1.w += __shfl_xor(cs1.w, 32);
    }
    if (lane < 16) {
        if (lane < KK) {
            red[wv][lane] = pse;
            red[wv][10 + lane] = py0;
            red[wv][20 + lane] = py1;
            red[wv][30 + lane] = py2;
        }
        if (FOLD) {
            // cs0 on lane l covers cols [4l,4l+4); cs1 covers [64+4l, 64+4l+4)
            colred4[wv][0][lane] = cs0;
            colred4[wv][1][lane] = cs1;
        }
    }
    __syncthreads();
    if (tid < 40) {
        float s = red[0][tid] + red[1][tid] + red[2][tid] + red[3][tid];
        spartp[((size_t)b * NT + tile) * 40 + tid] = s;
    }
    if (FOLD && tid < DD) {
        // col == tid: j = tid>>6 selects cs0/cs1, ll = (tid&63)>>2, c = tid&3
        int j = tid >> 6, cc = tid & 63, ll = cc >> 2, c = cc & 3;
        float s = 0.f;
#pragma unroll
        for (int w = 0; w < 4; ++w) s += ((const float*)&colred4[w][j][ll])[c];
        hpartdst[((size_t)b * NT + tile) * DD + tid] = s;
    }
}

// ---------------------------------------------------------------------------
// Kernel 4: reduce spart partials, finalize Y1/Y2, Kabsch (fp64 Jacobi SVD).
// grid 16 (one per batch), 128 threads. Unchanged (HW-verified).
__global__ __launch_bounds__(128) void k_final(const float* __restrict__ spart,
                                               float* __restrict__ out) {
    int b = blockIdx.x;
    int tid = threadIdx.x;
    __shared__ float acc[2][40];
    if (tid < 80) {
        int p = tid / 40, j = tid % 40;
        const float* sp = spart + (size_t)(p * NB + b) * NT * 40 + j;
        float s = 0.f;
        for (int tile = 0; tile < NT; ++tile) s += sp[(size_t)tile * 40];
        acc[p][j] = s;
    }
    __syncthreads();
    __shared__ float Ys[2][KK][3];
    if (tid < 2 * KK * 3) {
        int p = tid / 30;
        int r = tid % 30;
        int k = r / 3;
        int c = r % 3;
        float val = acc[p][10 + c * 10 + k] / acc[p][k];
        Ys[p][k][c] = val;
        out[((size_t)(b * 3 + p) * KK + k) * 3 + c] = val;
    }
    __syncthreads();
    if (tid == 0) {
        double P[KK][3], Q[KK][3];
        double c1[3] = {0, 0, 0}, c2[3] = {0, 0, 0};
        for (int i = 0; i < KK; ++i)
            for (int c = 0; c < 3; ++c) {
                P[i][c] = (double)Ys[0][i][c];
                Q[i][c] = (double)Ys[1][i][c];
                c1[c] += P[i][c];
                c2[c] += Q[i][c];
            }
        for (int c = 0; c < 3; ++c) { c1[c] /= KK; c2[c] /= KK; }
        double A0[3][3];
        for (int a = 0; a < 3; ++a)
            for (int c = 0; c < 3; ++c) {
                double s = 0;
                for (int i = 0; i < KK; ++i) s += (P[i][a] - c1[a]) * (Q[i][c] - c2[c]);
                A0[a][c] = s;
            }
        double Bm[3][3], V[3][3];
        for (int a = 0; a < 3; ++a)
            for (int c = 0; c < 3; ++c) { Bm[a][c] = A0[a][c]; V[a][c] = (a == c) ? 1.0 : 0.0; }
        for (int sweep = 0; sweep < 16; ++sweep)
            for (int p = 0; p < 2; ++p)
                for (int q = p + 1; q < 3; ++q) {
                    double al = 0, be = 0, ga = 0;
                    for (int r = 0; r < 3; ++r) {
                        al += Bm[r][p] * Bm[r][p];
                        be += Bm[r][q] * Bm[r][q];
                        ga += Bm[r][p] * Bm[r][q];
                    }
                    if (fabs(ga) < 1e-300) continue;
                    double zeta = (be - al) / (2.0 * ga);
                    double t = copysign(1.0, zeta) / (fabs(zeta) + sqrt(1.0 + zeta * zeta));
                    double cs = 1.0 / sqrt(1.0 + t * t);
                    double sn = cs * t;
                    for (int r = 0; r < 3; ++r) {
                        double bp = Bm[r][p], bq = Bm[r][q];
                        Bm[r][p] = cs * bp - sn * bq;
                        Bm[r][q] = sn * bp + cs * bq;
                        double vp = V[r][p], vq = V[r][q];
                        V[r][p] = cs * vp - sn * vq;
                        V[r][q] = sn * vp + cs * vq;
                    }
                }
        double sig[3];
        for (int j = 0; j < 3; ++j) {
            sig[j] = sqrt(Bm[0][j] * Bm[0][j] + Bm[1][j] * Bm[1][j] + Bm[2][j] * Bm[2][j]);
            if (sig[j] < 1e-300) sig[j] = 1e-300;
        }
        int jmin = 0;
        if (sig[1] < sig[jmin]) jmin = 1;
        if (sig[2] < sig[jmin]) jmin = 2;
        // sign(det(U @ Vt)) == sign(det(A0))
        double det = A0[0][0] * (A0[1][1] * A0[2][2] - A0[1][2] * A0[2][1])
                   - A0[0][1] * (A0[1][0] * A0[2][2] - A0[1][2] * A0[2][0])
                   + A0[0][2] * (A0[1][0] * A0[2][1] - A0[1][1] * A0[2][0]);
        double sgn = (det >= 0.0) ? 1.0 : -1.0;
        double R[3][3];
        for (int a = 0; a < 3; ++a)
            for (int c = 0; c < 3; ++c) {
                double s = 0;
                for (int j = 0; j < 3; ++j) {
                    double dj = (j == jmin) ? sgn : 1.0;
                    s += dj * (Bm[a][j] / sig[j]) * V[c][j];
                }
                R[a][c] = s;
            }
        for (int i = 0; i < KK; ++i)
            for (int c = 0; c < 3; ++c) {
                double s = c2[c];
                for (int a = 0; a < 3; ++a) s += (P[i][a] - c1[a]) * R[a][c];
                out[((size_t)(b * 3 + 2) * KK + i) * 3 + c] = (float)s;
            }
    }
}

// ---------------------------------------------------------------------------
// Pipeline: 3 streaming passes (402 MB logical):
//   sum(H2) -> v1 -> scores1(H1)+foldsum(H1) -> v2 -> scores2(H2) -> final
// 6 launches, no memset, no atomics.
extern "C" void kernel_launch(void* const* d_in, const int* in_sizes, int n_in,
                              void* d_out, int out_size, void* d_ws, size_t ws_size,
                              hipStream_t stream) {
    const float* H1 = (const float*)d_in[0];
    const float* H2 = (const float*)d_in[1];
    const float* X1 = (const float*)d_in[2];
    const float* X2 = (const float*)d_in[3];
    const float* W1 = (const float*)d_in[4];
    const float* W2 = (const float*)d_in[5];
    float* out = (float*)d_out;
    float* ws = (float*)d_ws;
    float* hpart2 = ws;                      // 262144 floats
    float* hpart1 = ws + 262144;             // 262144 floats
    float* v1     = ws + 524288;             // 20480 floats
    float* v2     = ws + 544768;             // 20480 floats
    float* spart  = ws + 565248;             // [2][NB][NT][40] = 163840 floats
    float* sp1 = spart;
    float* sp2 = spart + (size_t)NB * NT * 40;

    hipLaunchKernelGGL(k_sum,            dim3(2048), dim3(256), 0, stream, H2, hpart2);
    hipLaunchKernelGGL(k_v,              dim3(160),  dim3(128), 0, stream, W1, hpart2, v1);
    hipLaunchKernelGGL((k_scores<true>), dim3(2048), dim3(256), 0, stream,
                       H1, X1, v1, sp1, hpart1);
    hipLaunchKernelGGL(k_v,              dim3(160),  dim3(128), 0, stream, W2, hpart1, v2);
    hipLaunchKernelGGL((k_scores<false>),dim3(2048), dim3(256), 0, stream,
                       H2, X2, v2, sp2, (float*)nullptr);
    hipLaunchKernelGGL(k_final,          dim3(16),   dim3(128), 0, stream, spart, out);
}